// Round 1
// baseline (728.122 us; speedup 1.0000x reference)
//
#include <hip/hip_runtime.h>
#include <math.h>

#define PI2 6.28318530717958647692f

// Problem constants: B=32, CI=CO=64, H=W=128, M1=M2=32.
// Modes: kxi in [0,64): rows 0..31 (kx=kxi) and 96..127 (kx=kxi+64). ky in [0,32).
// Layouts (fp32, workspace):
//   Y  [bi=2048][h=128][ky=32]
//   Xf [bi=2048][kxi=64][ky=32]
//   T  [bo=2048][kxi=64][ky=32]
//   Z  [bo=2048][kxi=64][w'=65]
// out [b=32][o=64][h=128][w'=65]

// ---------------- Stage F1: x -> Y (row DFT over W, 32 modes) ----------------
__global__ __launch_bounds__(256) void k_f1(const float* __restrict__ x,
                                            float* __restrict__ yr, float* __restrict__ yi) {
    __shared__ float xs[128 * 128];  // swizzled: xs[h*128 + ((w+h)&127)]
    const int bi = blockIdx.x;
    const float* xp = x + (size_t)bi * 16384;
    const int t = threadIdx.x;
    for (int idx = t; idx < 16384; idx += 256) {
        int h = idx >> 7, w = idx & 127;
        xs[(h << 7) + ((w + h) & 127)] = xp[idx];
    }
    __syncthreads();
    const int kyg = t & 7, hg = t >> 3;
    const int ky0 = kyg * 4, h0 = hg * 4;
    float c[4], s[4], dc[4], ds[4];
    float ar[4][4], ai[4][4];
    for (int jk = 0; jk < 4; jk++) {
        float th = -PI2 * (float)(ky0 + jk) / 128.0f;
        sincosf(th, &ds[jk], &dc[jk]);
        c[jk] = 1.0f; s[jk] = 0.0f;
        for (int jh = 0; jh < 4; jh++) { ar[jh][jk] = 0.0f; ai[jh][jk] = 0.0f; }
    }
    for (int w = 0; w < 128; w++) {
        float xv[4];
#pragma unroll
        for (int jh = 0; jh < 4; jh++) {
            int h = h0 + jh;
            xv[jh] = xs[(h << 7) + ((w + h) & 127)];
        }
#pragma unroll
        for (int jk = 0; jk < 4; jk++) {
            float cc = c[jk], ss = s[jk];
#pragma unroll
            for (int jh = 0; jh < 4; jh++) {
                ar[jh][jk] += xv[jh] * cc;
                ai[jh][jk] += xv[jh] * ss;
            }
            c[jk] = cc * dc[jk] - ss * ds[jk];
            s[jk] = ss * dc[jk] + cc * ds[jk];
        }
    }
    float* yrp = yr + (size_t)bi * 4096;
    float* yip = yi + (size_t)bi * 4096;
    for (int jh = 0; jh < 4; jh++) {
        int h = h0 + jh;
        *(float4*)&yrp[h * 32 + ky0] = make_float4(ar[jh][0], ar[jh][1], ar[jh][2], ar[jh][3]);
        *(float4*)&yip[h * 32 + ky0] = make_float4(ai[jh][0], ai[jh][1], ai[jh][2], ai[jh][3]);
    }
}

// ---------------- Stage F2: Y -> Xf (col DFT over H, 64 modes) ----------------
__global__ __launch_bounds__(128) void k_f2(const float* __restrict__ yr, const float* __restrict__ yi,
                                            float* __restrict__ xfr, float* __restrict__ xfi) {
    __shared__ float2 ys[4096];  // [h][ky]
    const int bi = blockIdx.x;
    const int t = threadIdx.x;
    const float* yrp = yr + (size_t)bi * 4096;
    const float* yip = yi + (size_t)bi * 4096;
    for (int idx = t; idx < 4096; idx += 128) ys[idx] = make_float2(yrp[idx], yip[idx]);
    __syncthreads();
    const int kyg = t & 7, kxg = t >> 3;  // kxg 0..15
    const int ky0 = kyg * 4, kxi0 = kxg * 4;
    float c[4], s[4], dc[4], ds[4];
    float xr[4][4], xim[4][4];
    for (int jx = 0; jx < 4; jx++) {
        int kxi = kxi0 + jx;
        int kx = (kxi < 32) ? kxi : (kxi + 64);
        float th = -PI2 * (float)kx / 128.0f;
        sincosf(th, &ds[jx], &dc[jx]);
        c[jx] = 1.0f; s[jx] = 0.0f;
        for (int jy = 0; jy < 4; jy++) { xr[jx][jy] = 0.0f; xim[jx][jy] = 0.0f; }
    }
    for (int h = 0; h < 128; h++) {
        float2 y[4];
        const float2* pp = &ys[h * 32 + ky0];
#pragma unroll
        for (int jy = 0; jy < 4; jy++) y[jy] = pp[jy];
#pragma unroll
        for (int jx = 0; jx < 4; jx++) {
            float cc = c[jx], ss = s[jx];
#pragma unroll
            for (int jy = 0; jy < 4; jy++) {
                xr[jx][jy]  += cc * y[jy].x - ss * y[jy].y;
                xim[jx][jy] += cc * y[jy].y + ss * y[jy].x;
            }
            c[jx] = cc * dc[jx] - ss * ds[jx];
            s[jx] = ss * dc[jx] + cc * ds[jx];
        }
    }
    float* xrp = xfr + (size_t)bi * 2048;
    float* xip = xfi + (size_t)bi * 2048;
    for (int jx = 0; jx < 4; jx++) {
        int kxi = kxi0 + jx;
        *(float4*)&xrp[kxi * 32 + ky0] = make_float4(xr[jx][0], xr[jx][1], xr[jx][2], xr[jx][3]);
        *(float4*)&xip[kxi * 32 + ky0] = make_float4(xim[jx][0], xim[jx][1], xim[jx][2], xim[jx][3]);
    }
}

// ---------------- Stage M: channel mix, T = Xf @ conj(W) ----------------
__global__ __launch_bounds__(512) void k_mix(const float* __restrict__ xfr, const float* __restrict__ xfi,
                                             const float* __restrict__ w1r, const float* __restrict__ w1i,
                                             const float* __restrict__ w2r, const float* __restrict__ w2i,
                                             float* __restrict__ tr, float* __restrict__ ti) {
    __shared__ float2 xfs[8192];  // [8 b][32 i][32 ky] per stage
    const int kxi = blockIdx.x;       // 0..63
    const int b0 = blockIdx.y * 8;    // 4 groups of 8 b
    const int t = threadIdx.x;
    const int ky = t & 31, grp = t >> 5;  // grp 0..15
    const int o0 = grp * 4;
    const float* wr = (kxi < 32) ? w1r : w2r;
    const float* wi = (kxi < 32) ? w1i : w2i;
    const int kxim = kxi & 31;
    float accr[8][4], acci[8][4];
    for (int jb = 0; jb < 8; jb++)
        for (int jo = 0; jo < 4; jo++) { accr[jb][jo] = 0.0f; acci[jb][jo] = 0.0f; }

    for (int stage = 0; stage < 2; stage++) {
        const int ibase = stage * 32;
        __syncthreads();
        for (int idx = t; idx < 8192; idx += 512) {
            int b = idx >> 10, ii = (idx >> 5) & 31, kk = idx & 31;
            size_t g = ((size_t)(b0 + b) * 64 + (ibase + ii)) * 2048 + (size_t)kxi * 32 + kk;
            xfs[idx] = make_float2(xfr[g], xfi[g]);
        }
        __syncthreads();
        for (int ii = 0; ii < 32; ii++) {
            const int i = ibase + ii;
            float wr4[4], wi4[4];
#pragma unroll
            for (int jo = 0; jo < 4; jo++) {
                size_t g = ((size_t)i * 64 + (o0 + jo)) * 1024 + (size_t)kxim * 32 + ky;
                wr4[jo] = wr[g]; wi4[jo] = wi[g];
            }
#pragma unroll
            for (int jb = 0; jb < 8; jb++) {
                float2 xf = xfs[(jb << 10) + (ii << 5) + ky];
#pragma unroll
                for (int jo = 0; jo < 4; jo++) {
                    accr[jb][jo] += xf.x * wr4[jo] + xf.y * wi4[jo];
                    acci[jb][jo] += xf.y * wr4[jo] - xf.x * wi4[jo];
                }
            }
        }
    }
    for (int jb = 0; jb < 8; jb++)
        for (int jo = 0; jo < 4; jo++) {
            size_t g = ((size_t)(b0 + jb) * 64 + (o0 + jo)) * 2048 + (size_t)kxi * 32 + ky;
            tr[g] = accr[jb][jo];
            ti[g] = acci[jb][jo];
        }
}

// ---------------- Stage I1: T -> Z (inverse DFT over ky -> 65 cols) ----------------
__global__ __launch_bounds__(256) void k_i1(const float* __restrict__ tr, const float* __restrict__ ti,
                                            float* __restrict__ zr, float* __restrict__ zi) {
    __shared__ float2 ts[2048];  // [kxi][ky]
    const int bo = blockIdx.x, t = threadIdx.x;
    const float* trp = tr + (size_t)bo * 2048;
    const float* tip = ti + (size_t)bo * 2048;
    for (int idx = t; idx < 2048; idx += 256) ts[idx] = make_float2(trp[idx], tip[idx]);
    __syncthreads();
    float* zrp = zr + (size_t)bo * 4160;
    float* zip = zi + (size_t)bo * 4160;
    for (int p = t; p < 2080; p += 256) {
        int w = p % 65, kxi = p / 65;  // kxi 0..31, paired with kxi+32
        float dc, ds;
        sincosf(PI2 * (float)w / 65.0f, &ds, &dc);
        float c = 1.0f, s = 0.0f;
        float z1r = 0, z1i = 0, z2r = 0, z2i = 0;
        for (int ky = 0; ky < 32; ky++) {
            float2 t1 = ts[kxi * 32 + ky];
            float2 t2 = ts[(kxi + 32) * 32 + ky];
            z1r += t1.x * c - t1.y * s;
            z1i += t1.x * s + t1.y * c;
            z2r += t2.x * c - t2.y * s;
            z2i += t2.x * s + t2.y * c;
            float nc = c * dc - s * ds;
            s = s * dc + c * ds;
            c = nc;
        }
        zrp[kxi * 65 + w] = z1r; zip[kxi * 65 + w] = z1i;
        zrp[(kxi + 32) * 65 + w] = z2r; zip[(kxi + 32) * 65 + w] = z2i;
    }
}

// ---------------- Stage I2: Z -> out (inverse DFT over H, real part) ----------------
// Row pairing: slot kxi (row kxi) and slot kxi+32 (row kxi+96).
// e^{2pi i * 96 h/128} = (-i)^h, so A(h) = Z1 + (-i)^h * Z2, out = Re(e^{2pi i kxi h/128} * A).
__global__ __launch_bounds__(256) void k_i2(const float* __restrict__ zr, const float* __restrict__ zi,
                                            float* __restrict__ out) {
    __shared__ float2 zs[64 * 68];  // [kxi][w'], padded to 68 (zero pad cols 65..67)
    const int bo = blockIdx.x, t = threadIdx.x;
    const float* zrp = zr + (size_t)bo * 4160;
    const float* zip = zi + (size_t)bo * 4160;
    for (int idx = t; idx < 64 * 68; idx += 256) {
        int kxi = idx / 68, w = idx % 68;
        float2 v = make_float2(0.0f, 0.0f);
        if (w < 65) v = make_float2(zrp[kxi * 65 + w], zip[kxi * 65 + w]);
        zs[idx] = v;
    }
    __syncthreads();
    float* op = out + (size_t)bo * 8320;
    const float scale = 1.0f / 8320.0f;  // 1/(128*65)
    for (int tile = t; tile < 544; tile += 256) {  // 32 hg * 17 wg
        int hg = tile / 17, wg = tile % 17;
        int h0 = hg * 4, w0 = wg * 4;
        float c[4], s[4], dc[4], ds[4], acc[4][4];
        for (int j = 0; j < 4; j++) {
            sincosf(PI2 * (float)(h0 + j) / 128.0f, &ds[j], &dc[j]);
            c[j] = 1.0f; s[j] = 0.0f;
            for (int k = 0; k < 4; k++) acc[j][k] = 0.0f;
        }
        for (int kxi = 0; kxi < 32; kxi++) {
            float2 z1[4], z2[4];
            const float2* p1 = &zs[kxi * 68 + w0];
            const float2* p2 = &zs[(kxi + 32) * 68 + w0];
#pragma unroll
            for (int k = 0; k < 4; k++) { z1[k] = p1[k]; z2[k] = p2[k]; }
#pragma unroll
            for (int k = 0; k < 4; k++) {
                float a0r = z1[k].x + z2[k].x, a0i = z1[k].y + z2[k].y;   // h%4==0: +Z2
                float a1r = z1[k].x + z2[k].y, a1i = z1[k].y - z2[k].x;   // h%4==1: -i*Z2
                float a2r = z1[k].x - z2[k].x, a2i = z1[k].y - z2[k].y;   // h%4==2: -Z2
                float a3r = z1[k].x - z2[k].y, a3i = z1[k].y + z2[k].x;   // h%4==3: +i*Z2
                acc[0][k] += c[0] * a0r - s[0] * a0i;
                acc[1][k] += c[1] * a1r - s[1] * a1i;
                acc[2][k] += c[2] * a2r - s[2] * a2i;
                acc[3][k] += c[3] * a3r - s[3] * a3i;
            }
#pragma unroll
            for (int j = 0; j < 4; j++) {
                float nc = c[j] * dc[j] - s[j] * ds[j];
                s[j] = s[j] * dc[j] + c[j] * ds[j];
                c[j] = nc;
            }
        }
        for (int j = 0; j < 4; j++)
            for (int k = 0; k < 4; k++) {
                int w = w0 + k;
                if (w < 65) op[(h0 + j) * 65 + w] = acc[j][k] * scale;
            }
    }
}

extern "C" void kernel_launch(void* const* d_in, const int* in_sizes, int n_in,
                              void* d_out, int out_size, void* d_ws, size_t ws_size,
                              hipStream_t stream) {
    const float* x   = (const float*)d_in[0];
    const float* w1r = (const float*)d_in[1];
    const float* w1i = (const float*)d_in[2];
    const float* w2r = (const float*)d_in[3];
    const float* w2i = (const float*)d_in[4];
    float* ws = (float*)d_ws;

    // Region A (reused): Y (F1->F2) then Z (I1->I2). Slot size = max(Y,Z) = 8,519,680 floats.
    float* yr = ws + 0;
    float* yi = ws + 8519680;
    float* zr = ws + 0;
    float* zi = ws + 8519680;
    // Region B: Xf; Region C: T.
    float* xfr = ws + 17039360;
    float* xfi = ws + 21233664;
    float* tr  = ws + 25427968;
    float* ti  = ws + 29622272;
    float* out = (float*)d_out;

    k_f1<<<2048, 256, 0, stream>>>(x, yr, yi);
    k_f2<<<2048, 128, 0, stream>>>(yr, yi, xfr, xfi);
    k_mix<<<dim3(64, 4), 512, 0, stream>>>(xfr, xfi, w1r, w1i, w2r, w2i, tr, ti);
    k_i1<<<2048, 256, 0, stream>>>(tr, ti, zr, zi);
    k_i2<<<2048, 256, 0, stream>>>(zr, zi, out);
}

// Round 2
// 644.121 us; speedup vs baseline: 1.1304x; 1.1304x over previous
//
#include <hip/hip_runtime.h>
#include <math.h>

#define PI2 6.28318530717958647692f

// Problem constants: B=32, CI=CO=64, H=W=128, M1=M2=32.
// Modes: kxi in [0,64): rows 0..31 (kx=kxi) and 96..127 (kx=kxi+64). ky in [0,32).
// Interleaved complex intermediates (float2 = {re, im}):
//   Y  [bi=2048][h=128][ky=32]   (buf1)
//   Xf [bi=2048][kxi=64][ky=32]  (buf2)
//   T  [bo=2048][kxi=64][ky=32]  (buf1)
//   Z  [bo=2048][kxi=64][w'=65]  (buf2)
// out [b=32][o=64][h=128][w'=65] fp32

// ---------------- Stage F1: x -> Y (row DFT over W, 32 modes) ----------------
// Block: one (bi, h-half): 64 rows. LDS 32 KiB (swizzled, conflict-free).
// Thread: 2 h x 4 ky. Occupancy target: 5 blocks/CU (LDS) = 20 waves/CU.
__global__ __launch_bounds__(256) void k_f1(const float* __restrict__ x,
                                            float2* __restrict__ y) {
    __shared__ float xs[64 * 128];  // xs[hl*128 + ((w+hl)&127)]
    const int bi = blockIdx.x;
    const int hbase = blockIdx.y * 64;
    const float* xp = x + (size_t)bi * 16384 + (size_t)hbase * 128;
    const int t = threadIdx.x;
    for (int idx = t * 4; idx < 8192; idx += 1024) {
        int hl = idx >> 7, w = idx & 127;
        float4 v = *(const float4*)&xp[idx];
        xs[(hl << 7) + ((w + 0 + hl) & 127)] = v.x;
        xs[(hl << 7) + ((w + 1 + hl) & 127)] = v.y;
        xs[(hl << 7) + ((w + 2 + hl) & 127)] = v.z;
        xs[(hl << 7) + ((w + 3 + hl) & 127)] = v.w;
    }
    __syncthreads();
    const int kyg = t & 7, hg = t >> 3;
    const int ky0 = kyg * 4, hl0 = hg * 2;
    float c[4], s[4], dc[4], ds[4];
    float ar[2][4], ai[2][4];
    for (int jk = 0; jk < 4; jk++) {
        float th = -PI2 * (float)(ky0 + jk) / 128.0f;
        sincosf(th, &ds[jk], &dc[jk]);
        c[jk] = 1.0f; s[jk] = 0.0f;
        for (int jh = 0; jh < 2; jh++) { ar[jh][jk] = 0.0f; ai[jh][jk] = 0.0f; }
    }
    const int base0 = hl0 << 7, base1 = (hl0 + 1) << 7;
    int wp0 = hl0 & 127, wp1 = (hl0 + 1) & 127;
#pragma unroll 4
    for (int w = 0; w < 128; w++) {
        float xv0 = xs[base0 + wp0];
        float xv1 = xs[base1 + wp1];
        wp0 = (wp0 + 1) & 127;
        wp1 = (wp1 + 1) & 127;
#pragma unroll
        for (int jk = 0; jk < 4; jk++) {
            float cc = c[jk], ss = s[jk];
            ar[0][jk] += xv0 * cc;
            ai[0][jk] += xv0 * ss;
            ar[1][jk] += xv1 * cc;
            ai[1][jk] += xv1 * ss;
            c[jk] = cc * dc[jk] - ss * ds[jk];
            s[jk] = ss * dc[jk] + cc * ds[jk];
        }
    }
    float2* yp = y + (size_t)bi * 4096;
    for (int jh = 0; jh < 2; jh++) {
        int h = hbase + hl0 + jh;
#pragma unroll
        for (int jk = 0; jk < 4; jk++)
            yp[h * 32 + ky0 + jk] = make_float2(ar[jh][jk], ai[jh][jk]);
    }
}

// ---------------- Stage F2: Y -> Xf (col DFT over H, 64 modes) ----------------
// Block: one bi image. 256 threads: 8 kyg x 32 kxg; thread = 2 kxi x 4 ky.
__global__ __launch_bounds__(256) void k_f2(const float2* __restrict__ y,
                                            float2* __restrict__ xf) {
    __shared__ float2 ys[4096];  // [h][ky], 32 KiB
    const int bi = blockIdx.x;
    const int t = threadIdx.x;
    const float2* yp = y + (size_t)bi * 4096;
    for (int idx = t; idx < 4096; idx += 256) ys[idx] = yp[idx];
    __syncthreads();
    const int kyg = t & 7, kxg = t >> 3;  // kxg 0..31
    const int ky0 = kyg * 4, kxi0 = kxg * 2;
    float c[2], s[2], dc[2], ds[2];
    float xr[2][4], xim[2][4];
    for (int jx = 0; jx < 2; jx++) {
        int kxi = kxi0 + jx;
        int kx = (kxi < 32) ? kxi : (kxi + 64);
        float th = -PI2 * (float)kx / 128.0f;
        sincosf(th, &ds[jx], &dc[jx]);
        c[jx] = 1.0f; s[jx] = 0.0f;
        for (int jy = 0; jy < 4; jy++) { xr[jx][jy] = 0.0f; xim[jx][jy] = 0.0f; }
    }
#pragma unroll 2
    for (int h = 0; h < 128; h++) {
        float2 yv[4];
        const float2* pp = &ys[h * 32 + ky0];
#pragma unroll
        for (int jy = 0; jy < 4; jy++) yv[jy] = pp[jy];
#pragma unroll
        for (int jx = 0; jx < 2; jx++) {
            float cc = c[jx], ss = s[jx];
#pragma unroll
            for (int jy = 0; jy < 4; jy++) {
                xr[jx][jy]  += cc * yv[jy].x - ss * yv[jy].y;
                xim[jx][jy] += cc * yv[jy].y + ss * yv[jy].x;
            }
            c[jx] = cc * dc[jx] - ss * ds[jx];
            s[jx] = ss * dc[jx] + cc * ds[jx];
        }
    }
    float2* xp = xf + (size_t)bi * 2048;
    for (int jx = 0; jx < 2; jx++) {
        int kxi = kxi0 + jx;
#pragma unroll
        for (int jy = 0; jy < 4; jy++)
            xp[kxi * 32 + ky0 + jy] = make_float2(xr[jx][jy], xim[jx][jy]);
    }
}

// ---------------- Stage M: channel mix, T = Xf @ conj(W) ----------------
__global__ __launch_bounds__(512) void k_mix(const float2* __restrict__ xf,
                                             const float* __restrict__ w1r, const float* __restrict__ w1i,
                                             const float* __restrict__ w2r, const float* __restrict__ w2i,
                                             float2* __restrict__ tt) {
    __shared__ float2 xfs[8192];  // [8 b][32 i][32 ky] per stage, 64 KiB
    const int kxi = blockIdx.x;       // 0..63
    const int b0 = blockIdx.y * 8;    // 4 groups of 8 b
    const int t = threadIdx.x;
    const int ky = t & 31, grp = t >> 5;  // grp 0..15
    const int o0 = grp * 4;
    const float* wr = (kxi < 32) ? w1r : w2r;
    const float* wi = (kxi < 32) ? w1i : w2i;
    const int kxim = kxi & 31;
    float accr[8][4], acci[8][4];
    for (int jb = 0; jb < 8; jb++)
        for (int jo = 0; jo < 4; jo++) { accr[jb][jo] = 0.0f; acci[jb][jo] = 0.0f; }

    for (int stage = 0; stage < 2; stage++) {
        const int ibase = stage * 32;
        __syncthreads();
        for (int idx = t; idx < 8192; idx += 512) {
            int b = idx >> 10, ii = (idx >> 5) & 31, kk = idx & 31;
            size_t g = ((size_t)(b0 + b) * 64 + (ibase + ii)) * 2048 + (size_t)kxi * 32 + kk;
            xfs[idx] = xf[g];
        }
        __syncthreads();
        for (int ii = 0; ii < 32; ii++) {
            const int i = ibase + ii;
            float wr4[4], wi4[4];
#pragma unroll
            for (int jo = 0; jo < 4; jo++) {
                size_t g = ((size_t)i * 64 + (o0 + jo)) * 1024 + (size_t)kxim * 32 + ky;
                wr4[jo] = wr[g]; wi4[jo] = wi[g];
            }
#pragma unroll
            for (int jb = 0; jb < 8; jb++) {
                float2 xv = xfs[(jb << 10) + (ii << 5) + ky];
#pragma unroll
                for (int jo = 0; jo < 4; jo++) {
                    accr[jb][jo] += xv.x * wr4[jo] + xv.y * wi4[jo];
                    acci[jb][jo] += xv.y * wr4[jo] - xv.x * wi4[jo];
                }
            }
        }
    }
    for (int jb = 0; jb < 8; jb++)
        for (int jo = 0; jo < 4; jo++) {
            size_t g = ((size_t)(b0 + jb) * 64 + (o0 + jo)) * 2048 + (size_t)kxi * 32 + ky;
            tt[g] = make_float2(accr[jb][jo], acci[jb][jo]);
        }
}

// ---------------- Stage I1: T -> Z (inverse DFT over ky -> 65 cols) ----------------
__global__ __launch_bounds__(256) void k_i1(const float2* __restrict__ tt,
                                            float2* __restrict__ z) {
    __shared__ float2 ts[2048];  // [kxi][ky], 16 KiB
    const int bo = blockIdx.x, t = threadIdx.x;
    const float2* tp = tt + (size_t)bo * 2048;
    for (int idx = t; idx < 2048; idx += 256) ts[idx] = tp[idx];
    __syncthreads();
    float2* zp = z + (size_t)bo * 4160;
    for (int p = t; p < 2080; p += 256) {
        int w = p % 65, kxi = p / 65;  // kxi 0..31, paired with kxi+32
        float dc, ds;
        sincosf(PI2 * (float)w / 65.0f, &ds, &dc);
        float c = 1.0f, s = 0.0f;
        float z1r = 0, z1i = 0, z2r = 0, z2i = 0;
        for (int ky = 0; ky < 32; ky++) {
            float2 t1 = ts[kxi * 32 + ky];
            float2 t2 = ts[(kxi + 32) * 32 + ky];
            z1r += t1.x * c - t1.y * s;
            z1i += t1.x * s + t1.y * c;
            z2r += t2.x * c - t2.y * s;
            z2i += t2.x * s + t2.y * c;
            float nc = c * dc - s * ds;
            s = s * dc + c * ds;
            c = nc;
        }
        zp[kxi * 65 + w] = make_float2(z1r, z1i);
        zp[(kxi + 32) * 65 + w] = make_float2(z2r, z2i);
    }
}

// ---------------- Stage I2: Z -> out (inverse DFT over H, real part) ----------------
// Row pairing: slot kxi (row kxi) and slot kxi+32 (row kxi+96).
// e^{2pi i * 96 h/128} = (-i)^h, so A(h) = Z1 + (-i)^h * Z2, out = Re(e^{2pi i kxi h/128} * A).
__global__ __launch_bounds__(256) void k_i2(const float2* __restrict__ z,
                                            float* __restrict__ out) {
    __shared__ float2 zs[64 * 68];  // [kxi][w'], padded to 68 (zero pad cols 65..67)
    const int bo = blockIdx.x, t = threadIdx.x;
    const float2* zp = z + (size_t)bo * 4160;
    for (int idx = t; idx < 64 * 68; idx += 256) {
        int kxi = idx / 68, w = idx % 68;
        float2 v = make_float2(0.0f, 0.0f);
        if (w < 65) v = zp[kxi * 65 + w];
        zs[idx] = v;
    }
    __syncthreads();
    float* op = out + (size_t)bo * 8320;
    const float scale = 1.0f / 8320.0f;  // 1/(128*65)
    for (int tile = t; tile < 544; tile += 256) {  // 32 hg * 17 wg
        int hg = tile / 17, wg = tile % 17;
        int h0 = hg * 4, w0 = wg * 4;
        float c[4], s[4], dc[4], ds[4], acc[4][4];
        for (int j = 0; j < 4; j++) {
            sincosf(PI2 * (float)(h0 + j) / 128.0f, &ds[j], &dc[j]);
            c[j] = 1.0f; s[j] = 0.0f;
            for (int k = 0; k < 4; k++) acc[j][k] = 0.0f;
        }
        for (int kxi = 0; kxi < 32; kxi++) {
            float2 z1[4], z2[4];
            const float2* p1 = &zs[kxi * 68 + w0];
            const float2* p2 = &zs[(kxi + 32) * 68 + w0];
#pragma unroll
            for (int k = 0; k < 4; k++) { z1[k] = p1[k]; z2[k] = p2[k]; }
#pragma unroll
            for (int k = 0; k < 4; k++) {
                float a0r = z1[k].x + z2[k].x, a0i = z1[k].y + z2[k].y;   // h%4==0: +Z2
                float a1r = z1[k].x + z2[k].y, a1i = z1[k].y - z2[k].x;   // h%4==1: -i*Z2
                float a2r = z1[k].x - z2[k].x, a2i = z1[k].y - z2[k].y;   // h%4==2: -Z2
                float a3r = z1[k].x - z2[k].y, a3i = z1[k].y + z2[k].x;   // h%4==3: +i*Z2
                acc[0][k] += c[0] * a0r - s[0] * a0i;
                acc[1][k] += c[1] * a1r - s[1] * a1i;
                acc[2][k] += c[2] * a2r - s[2] * a2i;
                acc[3][k] += c[3] * a3r - s[3] * a3i;
            }
#pragma unroll
            for (int j = 0; j < 4; j++) {
                float nc = c[j] * dc[j] - s[j] * ds[j];
                s[j] = s[j] * dc[j] + c[j] * ds[j];
                c[j] = nc;
            }
        }
        for (int j = 0; j < 4; j++)
            for (int k = 0; k < 4; k++) {
                int w = w0 + k;
                if (w < 65) op[(h0 + j) * 65 + w] = acc[j][k] * scale;
            }
    }
}

extern "C" void kernel_launch(void* const* d_in, const int* in_sizes, int n_in,
                              void* d_out, int out_size, void* d_ws, size_t ws_size,
                              hipStream_t stream) {
    const float* x   = (const float*)d_in[0];
    const float* w1r = (const float*)d_in[1];
    const float* w1i = (const float*)d_in[2];
    const float* w2r = (const float*)d_in[3];
    const float* w2i = (const float*)d_in[4];
    float2* ws = (float2*)d_ws;

    // buf1: Y (F1->F2) then T (mix->I1). Size max(8388608, 4194304) float2.
    // buf2: Xf (F2->mix) then Z (I1->I2). Size max(4194304, 8519680) float2.
    float2* ya  = ws;
    float2* ta  = ws;
    float2* xfa = ws + 8388608;
    float2* za  = ws + 8388608;
    float* out = (float*)d_out;

    k_f1<<<dim3(2048, 2), 256, 0, stream>>>(x, ya);
    k_f2<<<2048, 256, 0, stream>>>(ya, xfa);
    k_mix<<<dim3(64, 4), 512, 0, stream>>>(xfa, w1r, w1i, w2r, w2i, ta);
    k_i1<<<2048, 256, 0, stream>>>(ta, za);
    k_i2<<<2048, 256, 0, stream>>>(za, out);
}